// Round 4
// baseline (808.974 us; speedup 1.0000x reference)
//
#include <hip/hip_runtime.h>
#include <stdint.h>

#define D_ 128
#define NB_ 20
#define SCAN_B 1024
#define SEG_BLOCKS 2048
#define NWAVES (SEG_BLOCKS * 256 / 64)

typedef __bf16 bf16x8 __attribute__((ext_vector_type(8)));
typedef float f32x4 __attribute__((ext_vector_type(4)));
typedef float f32x2 __attribute__((ext_vector_type(2)));

// fast silu: x * rcp(1+exp(-x)); v_rcp_f32 rel-err ~2^-22, fine at bf16 tolerance
__device__ __forceinline__ float silu_f(float x) {
  return x * __builtin_amdgcn_rcpf(1.0f + __expf(-x));
}
__device__ __forceinline__ f32x2 silu2(f32x2 x) {
  return (f32x2){silu_f(x.x), silu_f(x.y)};
}
__device__ __forceinline__ f32x2 fsplat(float x) { return (f32x2){x, x}; }

__device__ __forceinline__ unsigned short f2bf(float f) {
  unsigned int x = __float_as_uint(f);
  return (unsigned short)((x + 0x7fffu + ((x >> 16) & 1u)) >> 16);
}
// unpack a uint holding two bf16 (low = lane ch0, high = ch1) into f32x2
__device__ __forceinline__ f32x2 bfpair(unsigned u) {
  return (f32x2){__uint_as_float(u << 16), __uint_as_float(u & 0xffff0000u)};
}
__device__ __forceinline__ unsigned packbf(f32x2 v) {
  return ((unsigned)f2bf(v.y) << 16) | (unsigned)f2bf(v.x);
}

// ---------------------------------------------------------------------------
// prep ranges:
//  [0, 2688):           Mfold = A2@W1c (20x128), b1p = b1 + ab2@W1c
//  [2688, 19072):       W2uT bf16: W2uT[n*128+k] = (W2@Wu)[k][n]
//  [19072, 19200):      c2 = b2 @ Wu
//  [19200, 51968):      W1T bf16: W1T[half*128+n][k] = W1[half*128+k][n]
__global__ __launch_bounds__(256) void prep_kernel(
    const float* __restrict__ A2, const float* __restrict__ ab2,
    const float* __restrict__ W1, const float* __restrict__ b1,
    const float* __restrict__ W2, const float* __restrict__ Wu,
    const float* __restrict__ b2,
    float* __restrict__ Mfold, float* __restrict__ b1p,
    unsigned short* __restrict__ W2uT, float* __restrict__ c2,
    unsigned short* __restrict__ W1T) {
  int tid = blockIdx.x * blockDim.x + threadIdx.x;
  if (tid < 21 * D_) {
    int r = tid >> 7, c = tid & (D_ - 1);
    if (r < NB_) {
      float acc = 0.f;
      for (int j = 0; j < NB_; ++j) acc += A2[r * NB_ + j] * W1[(2 * D_ + j) * D_ + c];
      Mfold[r * D_ + c] = acc;
    } else {
      float acc = b1[c];
      for (int j = 0; j < NB_; ++j) acc += ab2[j] * W1[(2 * D_ + j) * D_ + c];
      b1p[c] = acc;
    }
  } else if (tid < 2688 + 16384) {
    int i = tid - 2688;
    int n = i >> 7, k = i & 127;
    float acc = 0.f;
    for (int m = 0; m < D_; ++m) acc += W2[k * D_ + m] * Wu[m * D_ + n];
    W2uT[i] = f2bf(acc);
  } else if (tid < 19072 + 128) {
    int n = tid - 19072;
    float acc = 0.f;
    for (int m = 0; m < D_; ++m) acc += b2[m] * Wu[m * D_ + n];
    c2[n] = acc;
  } else if (tid < 19200 + 32768) {
    int i = tid - 19200;
    int r = i >> 7, k = i & 127;
    int half = r >> 7, n = r & 127;
    W1T[i] = f2bf(W1[(size_t)(half * 128 + k) * D_ + n]);
  }
}

// ---------------------------------------------------------------------------
// MFMA pq: P = edge_attr @ W1[0:128], Q = edge_attr @ W1[128:256], bf16 out.
// edge_attr read-once (nt load); P read-once downstream (nt store); Q stays
// cacheable (5x average reuse by seg's gathers).
__global__ __launch_bounds__(256) void pq_mfma(const float* __restrict__ edge_attr,
                                               const unsigned short* __restrict__ W1T,
                                               unsigned short* __restrict__ P,
                                               unsigned short* __restrict__ Q, int E) {
  const int lane = threadIdx.x & 63;
  const int wave = threadIdx.x >> 6;
  const int e0 = (blockIdx.x * 4 + wave) * 16;
  if (e0 >= E) return;
  const int row = lane & 15;
  const int quad = lane >> 4;
  int e = e0 + row; if (e >= E) e = E - 1;

  union { bf16x8 v; unsigned short u[8]; } afr[4];
  const float* arow = edge_attr + (size_t)e * D_ + quad * 8;
#pragma unroll
  for (int kt = 0; kt < 4; ++kt) {
    f32x4 f0 = __builtin_nontemporal_load((const f32x4*)(arow + kt * 32));
    f32x4 f1 = __builtin_nontemporal_load((const f32x4*)(arow + kt * 32 + 4));
    afr[kt].u[0] = f2bf(f0[0]); afr[kt].u[1] = f2bf(f0[1]);
    afr[kt].u[2] = f2bf(f0[2]); afr[kt].u[3] = f2bf(f0[3]);
    afr[kt].u[4] = f2bf(f1[0]); afr[kt].u[5] = f2bf(f1[1]);
    afr[kt].u[6] = f2bf(f1[2]); afr[kt].u[7] = f2bf(f1[3]);
  }
#pragma unroll
  for (int half = 0; half < 2; ++half) {
    unsigned short* Obase = half ? Q : P;
#pragma unroll
    for (int nt = 0; nt < 8; ++nt) {
      const unsigned short* wrow =
          W1T + ((size_t)(half * 128 + nt * 16 + row)) * 128 + quad * 8;
      f32x4 acc = {0.f, 0.f, 0.f, 0.f};
#pragma unroll
      for (int kt = 0; kt < 4; ++kt) {
        bf16x8 bfr = *(const bf16x8*)(wrow + kt * 32);
        acc = __builtin_amdgcn_mfma_f32_16x16x32_bf16(afr[kt].v, bfr, acc, 0, 0, 0);
      }
      int n = nt * 16 + row;
#pragma unroll
      for (int i = 0; i < 4; ++i) {
        int er = e0 + quad * 4 + i;
        if (er < E) {
          if (half == 0)
            __builtin_nontemporal_store(f2bf(acc[i]), &Obase[(size_t)er * D_ + n]);
          else
            Obase[(size_t)er * D_ + n] = f2bf(acc[i]);
        }
      }
    }
  }
}

// ---------------------------------------------------------------------------
// Counting sort by e_ij
__global__ void hist_kernel(const int* __restrict__ tbe, int* __restrict__ cnt, int T_) {
  int t = blockIdx.x * blockDim.x + threadIdx.x;
  if (t < T_) atomicAdd(&cnt[((const int2*)tbe)[t].x], 1);
}

__global__ __launch_bounds__(SCAN_B) void scan1_kernel(const int* __restrict__ cnt,
                                                       int* __restrict__ pre,
                                                       int* __restrict__ bsum, int E) {
  __shared__ int lds[SCAN_B];
  int tid = threadIdx.x, i = blockIdx.x * SCAN_B + tid;
  int v = (i < E) ? cnt[i] : 0;
  lds[tid] = v;
  __syncthreads();
  for (int d = 1; d < SCAN_B; d <<= 1) {
    int add = (tid >= d) ? lds[tid - d] : 0;
    __syncthreads();
    lds[tid] += add;
    __syncthreads();
  }
  if (i < E) pre[i] = lds[tid] - v;
  if (tid == SCAN_B - 1) bsum[blockIdx.x] = lds[tid];
}

__global__ void scan2_kernel(int* __restrict__ bsum, int nb) {
  __shared__ int lds[256];
  int tid = threadIdx.x;
  int v = (tid < nb) ? bsum[tid] : 0;
  lds[tid] = v;
  __syncthreads();
  for (int d = 1; d < 256; d <<= 1) {
    int add = (tid >= d) ? lds[tid - d] : 0;
    __syncthreads();
    lds[tid] += add;
    __syncthreads();
  }
  if (tid < nb) bsum[tid] = lds[tid] - v;
}

// scan3 + wfill + seik2-pad-zero fused (saves 2 dispatches).
__global__ __launch_bounds__(SCAN_B) void scan3_wfill(
    const int* __restrict__ pre, const int* __restrict__ bsum,
    int* __restrict__ offs, int* __restrict__ cursor,
    int2* __restrict__ seik2, int* __restrict__ wstart,
    int E, int T_, int NW) {
  int i = blockIdx.x * SCAN_B + threadIdx.x;
  if (i < E) {
    int o = pre[i] + bsum[blockIdx.x];
    offs[i] = o;
    cursor[i] = o;
    int onext = (i + 1 < E) ? (pre[i + 1] + bsum[(i + 1) >> 10]) : T_;
    unsigned long long a = (unsigned long long)o * (unsigned long long)NW;
    unsigned long long b = (unsigned long long)onext * (unsigned long long)NW;
    int w_lo = (int)((a + T_ - 1) / (unsigned long long)T_);
    int w_hi = (int)((b + T_ - 1) / (unsigned long long)T_);
    for (int w = w_lo; w < w_hi; ++w) wstart[w] = i;
  }
  if (i == 0) offs[E] = T_;
  if (i < 8) seik2[T_ + i] = make_int2(0, 0);
}

// Light scatter: only the 8B index pair goes to the random position.
__global__ void scatter_kernel(const int* __restrict__ tbe, int* __restrict__ cursor,
                               int2* __restrict__ seik2, int T_) {
  int t = blockIdx.x * blockDim.x + threadIdx.x;
  if (t >= T_) return;
  int2 v = ((const int2*)tbe)[t];
  int pos = atomicAdd(&cursor[v.x], 1);
  seik2[pos] = make_int2(v.y, v.x);  // {e_ik, e_ij}
}

// Geometry pass in sorted order: coalesced 80B gT rows, nt stores (read-once).
__global__ __launch_bounds__(256) void geom_kernel(const int2* __restrict__ seik2,
                                                   const float* __restrict__ edge_vectors,
                                                   const float* __restrict__ A1,
                                                   const float* __restrict__ ab1,
                                                   float* __restrict__ gT, int T_) {
  int t = blockIdx.x * blockDim.x + threadIdx.x;
  if (t >= T_) return;
  int2 s = seik2[t];
  const float* vj = edge_vectors + 3 * (size_t)s.y;
  const float* vk = edge_vectors + 3 * (size_t)s.x;
  float jx = vj[0], jy = vj[1], jz = vj[2];
  float kx = vk[0], ky = vk[1], kz = vk[2];
  float lij = fmaxf(__builtin_amdgcn_sqrtf(jx * jx + jy * jy + jz * jz), 1e-6f);
  float lik = fmaxf(__builtin_amdgcn_sqrtf(kx * kx + ky * ky + kz * kz), 1e-6f);
  float cosv = (jx * kx + jy * ky + jz * kz) * __builtin_amdgcn_rcpf(lij * lik);
  cosv = fminf(fmaxf(cosv, -1.f), 1.f);
  union { f32x4 v4[5]; float f[NB_]; } gr;
#pragma unroll
  for (int k = 0; k < NB_; ++k)
    gr.f[k] = silu_f(lij * A1[k] + lik * A1[NB_ + k] + cosv * A1[2 * NB_ + k] + ab1[k]);
  f32x4* gp = (f32x4*)(gT + (size_t)t * NB_);
#pragma unroll
  for (int i = 0; i < 5; ++i) __builtin_nontemporal_store(gr.v4[i], gp + i);
}

// ---------------------------------------------------------------------------
// Flat-streamed segmented reduction. All single-use streams (P, G, s-out) are
// nontemporal so L3 stays reserved for the Q gather working set (51MB, ~5x
// reuse). Output rows are bf16 packed into the FRONT 256B of each 512B d_out
// row slot.
struct G5 { f32x4 a, b, c, d, e; };

__device__ __forceinline__ G5 loadG(const char* __restrict__ gc, int t) {
  const f32x4* p = (const f32x4*)(
      gc + 80u * (unsigned)__builtin_amdgcn_readfirstlane(t));
  G5 g;
  g.a = __builtin_nontemporal_load(p);
  g.b = __builtin_nontemporal_load(p + 1);
  g.c = __builtin_nontemporal_load(p + 2);
  g.d = __builtin_nontemporal_load(p + 3);
  g.e = __builtin_nontemporal_load(p + 4);
  return g;
}

__device__ __forceinline__ void body_acc(f32x2& acc, const f32x2 base,
                                         const G5& G, unsigned qw,
                                         const f32x2* __restrict__ m) {
  const float* Gf = (const float*)&G;
  f32x2 u = base + bfpair(qw);
  f32x2 ub = fsplat(0.f);
#pragma unroll
  for (int k = 0; k < NB_; k += 2) {
    u  += fsplat(Gf[k])     * m[k];
    ub += fsplat(Gf[k + 1]) * m[k + 1];
  }
  u += ub;
  acc += silu2(u);
}

__global__ __launch_bounds__(256, 6) void seg_kernel(
    const int* __restrict__ offs, const int2* __restrict__ seik2,
    const float* __restrict__ gT,
    const float* __restrict__ Mfold, const float* __restrict__ b1p,
    const unsigned short* __restrict__ P, const unsigned short* __restrict__ Q,
    const int* __restrict__ wstart,
    char* __restrict__ s_out, int E, int NW) {
  const int lane = threadIdx.x & 63;
  const int w = __builtin_amdgcn_readfirstlane(
      (int)((blockIdx.x * blockDim.x + threadIdx.x) >> 6));
  if (w >= NW) return;

  f32x2 m[NB_];
#pragma unroll
  for (int k = 0; k < NB_; ++k) {
    float2 t2 = *(const float2*)(Mfold + k * D_ + 2 * lane);
    m[k] = (f32x2){t2.x, t2.y};
  }
  const float2 bbt = *(const float2*)(b1p + 2 * lane);
  const f32x2 bb = (f32x2){bbt.x, bbt.y};

  int es = (w == 0) ? 0 : wstart[w];
  int ee = (w == NW - 1) ? E : wstart[w + 1];
  if (es >= ee) return;

  const char* Qc = (const char*)Q;
  const char* Pc = (const char*)P;
  const char* gc = (const char*)gT;
  const unsigned loff = (unsigned)lane * 4u;

  int e = es;
  int t = offs[es];
  const int tend = offs[ee];
  int nxt = offs[es + 1];

  unsigned pp = __builtin_nontemporal_load(
      (const unsigned*)(Pc + ((unsigned)e << 8) + loff));
  int epn = (e + 1 < E) ? e + 1 : E - 1;
  unsigned ppn = __builtin_nontemporal_load(
      (const unsigned*)(Pc + ((unsigned)epn << 8) + loff));
  f32x2 base = bfpair(pp) + bb;
  f32x2 acc = (f32x2){0.f, 0.f};

  if (t < tend) {
    // Q ring (depth 4) + eik lookahead; seik2 padded to T+8 (pad=0)
    int ek0 = seik2[t].x, ek1 = seik2[t + 1].x, ek2 = seik2[t + 2].x, ek3 = seik2[t + 3].x;
    unsigned q0 = *(const unsigned*)(Qc + ((unsigned)ek0 << 8) + loff);
    unsigned q1 = *(const unsigned*)(Qc + ((unsigned)ek1 << 8) + loff);
    unsigned q2 = *(const unsigned*)(Qc + ((unsigned)ek2 << 8) + loff);
    unsigned q3 = *(const unsigned*)(Qc + ((unsigned)ek3 << 8) + loff);
    int ekA = seik2[t + 4].x, ekB = seik2[t + 5].x, ekC = seik2[t + 6].x, ekD = seik2[t + 7].x;
    G5 Ga = loadG(gc, t);
    G5 Gb = loadG(gc, t + 1);

    while (t < tend) {
      // ---- even triplet (consumes Ga) ----
      while (t == nxt) {
        __builtin_nontemporal_store(
            packbf(acc), (unsigned*)(s_out + ((size_t)e << 9) + loff));
        acc = (f32x2){0.f, 0.f};
        ++e;
        nxt = offs[e + 1];
        base = bfpair(ppn) + bb;
        int ep = (e + 1 < E) ? e + 1 : E - 1;
        ppn = __builtin_nontemporal_load(
            (const unsigned*)(Pc + ((unsigned)ep << 8) + loff));
      }
      body_acc(acc, base, Ga, q0, m);
      q0 = q1; q1 = q2; q2 = q3;
      q3 = *(const unsigned*)(Qc + ((unsigned)ekA << 8) + loff);
      ekA = ekB; ekB = ekC; ekC = ekD;
      ekD = seik2[__builtin_amdgcn_readfirstlane(t + 8)].x;
      Ga = loadG(gc, t + 2);
      ++t;
      if (t >= tend) break;
      // ---- odd triplet (consumes Gb) ----
      while (t == nxt) {
        __builtin_nontemporal_store(
            packbf(acc), (unsigned*)(s_out + ((size_t)e << 9) + loff));
        acc = (f32x2){0.f, 0.f};
        ++e;
        nxt = offs[e + 1];
        base = bfpair(ppn) + bb;
        int ep = (e + 1 < E) ? e + 1 : E - 1;
        ppn = __builtin_nontemporal_load(
            (const unsigned*)(Pc + ((unsigned)ep << 8) + loff));
      }
      body_acc(acc, base, Gb, q0, m);
      q0 = q1; q1 = q2; q2 = q3;
      q3 = *(const unsigned*)(Qc + ((unsigned)ekA << 8) + loff);
      ekA = ekB; ekB = ekC; ekC = ekD;
      ekD = seik2[__builtin_amdgcn_readfirstlane(t + 8)].x;
      Gb = loadG(gc, t + 2);
      ++t;
    }
  }
  // flush current segment and any trailing empty segments in [e, ee)
  while (e < ee) {
    __builtin_nontemporal_store(
        packbf(acc), (unsigned*)(s_out + ((size_t)e << 9) + loff));
    acc = (f32x2){0.f, 0.f};
    ++e;
  }
}

// ---------------------------------------------------------------------------
// In-place MFMA: out[e] = s_bf16[e] @ W2u + cnt[e]*c2 + bu.
// s is bf16 in the front 256B of each 512B row slot of io; each wave reads
// its own 16 rows fully before writing them. nt loads/stores (single-use).
__global__ __launch_bounds__(256) void out_mfma(float* __restrict__ io,
                                                const unsigned short* __restrict__ W2uT,
                                                const float* __restrict__ c2,
                                                const float* __restrict__ bu,
                                                const int* __restrict__ cnt, int E) {
  const int lane = threadIdx.x & 63;
  const int wave = threadIdx.x >> 6;
  const int e0 = (blockIdx.x * 4 + wave) * 16;
  if (e0 >= E) return;
  const int row = lane & 15;
  const int quad = lane >> 4;
  int e = e0 + row; if (e >= E) e = E - 1;

  bf16x8 afr[4];
  const char* arow = (const char*)io + ((size_t)e << 9) + quad * 16;
#pragma unroll
  for (int kt = 0; kt < 4; ++kt)
    afr[kt] = __builtin_nontemporal_load((const bf16x8*)(arow + kt * 64));

  float nf[4];
#pragma unroll
  for (int i = 0; i < 4; ++i) {
    int er = e0 + quad * 4 + i;
    nf[i] = (float)cnt[(er < E) ? er : (E - 1)];
  }
#pragma unroll
  for (int nt = 0; nt < 8; ++nt) {
    const unsigned short* wrow = W2uT + ((size_t)(nt * 16 + row)) * 128 + quad * 8;
    f32x4 acc = {0.f, 0.f, 0.f, 0.f};
#pragma unroll
    for (int kt = 0; kt < 4; ++kt) {
      bf16x8 bfr = *(const bf16x8*)(wrow + kt * 32);
      acc = __builtin_amdgcn_mfma_f32_16x16x32_bf16(afr[kt], bfr, acc, 0, 0, 0);
    }
    int n = nt * 16 + row;
    float c2n = c2[n], bun = bu[n];
#pragma unroll
    for (int i = 0; i < 4; ++i) {
      int er = e0 + quad * 4 + i;
      if (er < E)
        __builtin_nontemporal_store(acc[i] + nf[i] * c2n + bun,
                                    &io[(size_t)er * D_ + n]);
    }
  }
}

// ---------------------------------------------------------------------------
extern "C" void kernel_launch(void* const* d_in, const int* in_sizes, int n_in,
                              void* d_out, int out_size, void* d_ws, size_t ws_size,
                              hipStream_t stream) {
  const float* edge_attr    = (const float*)d_in[0];
  const int*   tbe          = (const int*)d_in[2];
  const float* edge_vectors = (const float*)d_in[3];
  const float* A1  = (const float*)d_in[4];
  const float* ab1 = (const float*)d_in[5];
  const float* A2  = (const float*)d_in[6];
  const float* ab2 = (const float*)d_in[7];
  const float* W1  = (const float*)d_in[8];
  const float* b1  = (const float*)d_in[9];
  const float* W2  = (const float*)d_in[10];
  const float* b2  = (const float*)d_in[11];
  const float* Wu  = (const float*)d_in[12];
  const float* bu  = (const float*)d_in[13];
  const int E = in_sizes[0] / D_;
  const int T = in_sizes[2] / 2;
  float* out = (float*)d_out;

  char* w = (char*)d_ws;
  auto carve = [&](size_t bytes) -> char* {
    char* p = w;
    w += (bytes + 255) & ~(size_t)255;
    return p;
  };
  unsigned short* P = (unsigned short*)carve((size_t)E * D_ * 2);
  unsigned short* Q = (unsigned short*)carve((size_t)E * D_ * 2);
  float* gT   = (float*)carve(((size_t)T + 8) * NB_ * 4);   // +8 pad rows (unread values)
  int2* seik2 = (int2*)carve(((size_t)T + 8) * 8);          // +8 pad pairs (zeroed in scan3_wfill)
  int* cnt    = (int*)carve((size_t)E * 4);
  int* pre    = (int*)carve((size_t)E * 4);
  int* offs   = (int*)carve((size_t)(E + 1) * 4);
  int* cursor = (int*)carve((size_t)E * 4);
  int* bsum   = (int*)carve(1024 * 4);
  int* wstart = (int*)carve((size_t)NWAVES * 4);
  float* Mfold = (float*)carve(NB_ * D_ * 4);
  float* b1p   = (float*)carve(D_ * 4);
  unsigned short* W2uT = (unsigned short*)carve(D_ * D_ * 2);
  float* c2    = (float*)carve(D_ * 4);
  unsigned short* W1T = (unsigned short*)carve(256 * 128 * 2);

  const int nb_scan = (E + SCAN_B - 1) / SCAN_B;

  hipMemsetAsync(cnt, 0, (size_t)E * 4, stream);

  prep_kernel<<<(51968 + 255) / 256, 256, 0, stream>>>(A2, ab2, W1, b1, W2, Wu, b2,
                                                       Mfold, b1p, W2uT, c2, W1T);
  pq_mfma<<<(E + 63) / 64, 256, 0, stream>>>(edge_attr, W1T, P, Q, E);

  hist_kernel<<<(T + 255) / 256, 256, 0, stream>>>(tbe, cnt, T);
  scan1_kernel<<<nb_scan, SCAN_B, 0, stream>>>(cnt, pre, bsum, E);
  scan2_kernel<<<1, 256, 0, stream>>>(bsum, nb_scan);
  scan3_wfill<<<nb_scan, SCAN_B, 0, stream>>>(pre, bsum, offs, cursor, seik2,
                                              wstart, E, T, NWAVES);
  scatter_kernel<<<(T + 255) / 256, 256, 0, stream>>>(tbe, cursor, seik2, T);
  geom_kernel<<<(T + 255) / 256, 256, 0, stream>>>(seik2, edge_vectors, A1, ab1, gT, T);

  seg_kernel<<<SEG_BLOCKS, 256, 0, stream>>>(offs, seik2, gT, Mfold, b1p, P, Q,
                                             wstart, (char*)out, E, NWAVES);
  out_mfma<<<(E + 63) / 64, 256, 0, stream>>>(out, W2uT, c2, bu, cnt, E);
}

// Round 5
// 672.347 us; speedup vs baseline: 1.2032x; 1.2032x over previous
//
#include <hip/hip_runtime.h>
#include <stdint.h>

#define D_ 128
#define NB_ 20
#define SCAN_B 1024
#define SEG_BLOCKS 2048
#define NWAVES (SEG_BLOCKS * 256 / 64)

typedef __bf16 bf16x8 __attribute__((ext_vector_type(8)));
typedef float f32x4 __attribute__((ext_vector_type(4)));
typedef float f32x2 __attribute__((ext_vector_type(2)));

// fast silu: x * rcp(1+exp(-x)); v_rcp_f32 rel-err ~2^-22, fine at bf16 tolerance
__device__ __forceinline__ float silu_f(float x) {
  return x * __builtin_amdgcn_rcpf(1.0f + __expf(-x));
}
__device__ __forceinline__ f32x2 silu2(f32x2 x) {
  return (f32x2){silu_f(x.x), silu_f(x.y)};
}
__device__ __forceinline__ f32x2 fsplat(float x) { return (f32x2){x, x}; }

__device__ __forceinline__ unsigned short f2bf(float f) {
  unsigned int x = __float_as_uint(f);
  return (unsigned short)((x + 0x7fffu + ((x >> 16) & 1u)) >> 16);
}
// unpack a uint holding two bf16 (low = lane ch0, high = ch1) into f32x2
__device__ __forceinline__ f32x2 bfpair(unsigned u) {
  return (f32x2){__uint_as_float(u << 16), __uint_as_float(u & 0xffff0000u)};
}
__device__ __forceinline__ unsigned packbf(f32x2 v) {
  return ((unsigned)f2bf(v.y) << 16) | (unsigned)f2bf(v.x);
}

// ---------------------------------------------------------------------------
// prep ranges:
//  [0, 2688):           Mfold = A2@W1c (20x128), b1p = b1 + ab2@W1c
//  [2688, 19072):       W2uT bf16: W2uT[n*128+k] = (W2@Wu)[k][n]
//  [19072, 19200):      c2 = b2 @ Wu
//  [19200, 51968):      W1T bf16: W1T[half*128+n][k] = W1[half*128+k][n]
__global__ __launch_bounds__(256) void prep_kernel(
    const float* __restrict__ A2, const float* __restrict__ ab2,
    const float* __restrict__ W1, const float* __restrict__ b1,
    const float* __restrict__ W2, const float* __restrict__ Wu,
    const float* __restrict__ b2,
    float* __restrict__ Mfold, float* __restrict__ b1p,
    unsigned short* __restrict__ W2uT, float* __restrict__ c2,
    unsigned short* __restrict__ W1T) {
  int tid = blockIdx.x * blockDim.x + threadIdx.x;
  if (tid < 21 * D_) {
    int r = tid >> 7, c = tid & (D_ - 1);
    if (r < NB_) {
      float acc = 0.f;
      for (int j = 0; j < NB_; ++j) acc += A2[r * NB_ + j] * W1[(2 * D_ + j) * D_ + c];
      Mfold[r * D_ + c] = acc;
    } else {
      float acc = b1[c];
      for (int j = 0; j < NB_; ++j) acc += ab2[j] * W1[(2 * D_ + j) * D_ + c];
      b1p[c] = acc;
    }
  } else if (tid < 2688 + 16384) {
    int i = tid - 2688;
    // k uniform per 128-thread group (broadcast reads of W2 row), n coalesced
    int n = i & 127, k = i >> 7;
    float acc = 0.f;
    for (int m = 0; m < D_; ++m) acc += W2[k * D_ + m] * Wu[m * D_ + n];
    W2uT[n * 128 + k] = f2bf(acc);
  } else if (tid < 19072 + 128) {
    int n = tid - 19072;
    float acc = 0.f;
    for (int m = 0; m < D_; ++m) acc += b2[m] * Wu[m * D_ + n];
    c2[n] = acc;
  } else if (tid < 19200 + 32768) {
    int i = tid - 19200;
    int r = i >> 7, k = i & 127;
    int half = r >> 7, n = r & 127;
    W1T[i] = f2bf(W1[(size_t)(half * 128 + k) * D_ + n]);
  }
}

// ---------------------------------------------------------------------------
// MFMA pq: P = edge_attr @ W1[0:128], Q = edge_attr @ W1[128:256], bf16 out.
__global__ __launch_bounds__(256) void pq_mfma(const float* __restrict__ edge_attr,
                                               const unsigned short* __restrict__ W1T,
                                               unsigned short* __restrict__ P,
                                               unsigned short* __restrict__ Q, int E) {
  const int lane = threadIdx.x & 63;
  const int wave = threadIdx.x >> 6;
  const int e0 = (blockIdx.x * 4 + wave) * 16;
  if (e0 >= E) return;
  const int row = lane & 15;
  const int quad = lane >> 4;
  int e = e0 + row; if (e >= E) e = E - 1;

  union { bf16x8 v; unsigned short u[8]; } afr[4];
  const float* arow = edge_attr + (size_t)e * D_ + quad * 8;
#pragma unroll
  for (int kt = 0; kt < 4; ++kt) {
    float4 f0 = *(const float4*)(arow + kt * 32);
    float4 f1 = *(const float4*)(arow + kt * 32 + 4);
    afr[kt].u[0] = f2bf(f0.x); afr[kt].u[1] = f2bf(f0.y);
    afr[kt].u[2] = f2bf(f0.z); afr[kt].u[3] = f2bf(f0.w);
    afr[kt].u[4] = f2bf(f1.x); afr[kt].u[5] = f2bf(f1.y);
    afr[kt].u[6] = f2bf(f1.z); afr[kt].u[7] = f2bf(f1.w);
  }
#pragma unroll
  for (int half = 0; half < 2; ++half) {
    unsigned short* Obase = half ? Q : P;
#pragma unroll
    for (int nt = 0; nt < 8; ++nt) {
      const unsigned short* wrow =
          W1T + ((size_t)(half * 128 + nt * 16 + row)) * 128 + quad * 8;
      f32x4 acc = {0.f, 0.f, 0.f, 0.f};
#pragma unroll
      for (int kt = 0; kt < 4; ++kt) {
        bf16x8 bfr = *(const bf16x8*)(wrow + kt * 32);
        acc = __builtin_amdgcn_mfma_f32_16x16x32_bf16(afr[kt].v, bfr, acc, 0, 0, 0);
      }
      int n = nt * 16 + row;
#pragma unroll
      for (int i = 0; i < 4; ++i) {
        int er = e0 + quad * 4 + i;
        if (er < E) Obase[(size_t)er * D_ + n] = f2bf(acc[i]);
      }
    }
  }
}

// ---------------------------------------------------------------------------
// Counting sort by e_ij
__global__ void hist_kernel(const int* __restrict__ tbe, int* __restrict__ cnt, int T_) {
  int t = blockIdx.x * blockDim.x + threadIdx.x;
  if (t < T_) atomicAdd(&cnt[((const int2*)tbe)[t].x], 1);
}

__global__ __launch_bounds__(SCAN_B) void scan1_kernel(const int* __restrict__ cnt,
                                                       int* __restrict__ pre,
                                                       int* __restrict__ bsum, int E) {
  __shared__ int lds[SCAN_B];
  int tid = threadIdx.x, i = blockIdx.x * SCAN_B + tid;
  int v = (i < E) ? cnt[i] : 0;
  lds[tid] = v;
  __syncthreads();
  for (int d = 1; d < SCAN_B; d <<= 1) {
    int add = (tid >= d) ? lds[tid - d] : 0;
    __syncthreads();
    lds[tid] += add;
    __syncthreads();
  }
  if (i < E) pre[i] = lds[tid] - v;
  if (tid == SCAN_B - 1) bsum[blockIdx.x] = lds[tid];
}

__global__ void scan2_kernel(int* __restrict__ bsum, int nb) {
  __shared__ int lds[256];
  int tid = threadIdx.x;
  int v = (tid < nb) ? bsum[tid] : 0;
  lds[tid] = v;
  __syncthreads();
  for (int d = 1; d < 256; d <<= 1) {
    int add = (tid >= d) ? lds[tid - d] : 0;
    __syncthreads();
    lds[tid] += add;
    __syncthreads();
  }
  if (tid < nb) bsum[tid] = lds[tid] - v;
}

// scan3 + wfill + seik2-pad-zero fused.
__global__ __launch_bounds__(SCAN_B) void scan3_wfill(
    const int* __restrict__ pre, const int* __restrict__ bsum,
    int* __restrict__ offs, int* __restrict__ cursor,
    int2* __restrict__ seik2, int* __restrict__ wstart,
    int E, int T_, int NW) {
  int i = blockIdx.x * SCAN_B + threadIdx.x;
  if (i < E) {
    int o = pre[i] + bsum[blockIdx.x];
    offs[i] = o;
    cursor[i] = o;
    int onext = (i + 1 < E) ? (pre[i + 1] + bsum[(i + 1) >> 10]) : T_;
    unsigned long long a = (unsigned long long)o * (unsigned long long)NW;
    unsigned long long b = (unsigned long long)onext * (unsigned long long)NW;
    int w_lo = (int)((a + T_ - 1) / (unsigned long long)T_);
    int w_hi = (int)((b + T_ - 1) / (unsigned long long)T_);
    for (int w = w_lo; w < w_hi; ++w) wstart[w] = i;
  }
  if (i == 0) offs[E] = T_;
  if (i < 16) seik2[T_ + i] = make_int2(0, 0);
}

// Light scatter: only the 8B index pair goes to the random position.
__global__ void scatter_kernel(const int* __restrict__ tbe, int* __restrict__ cursor,
                               int2* __restrict__ seik2, int T_) {
  int t = blockIdx.x * blockDim.x + threadIdx.x;
  if (t >= T_) return;
  int2 v = ((const int2*)tbe)[t];
  int pos = atomicAdd(&cursor[v.x], 1);
  seik2[pos] = make_int2(v.y, v.x);  // {e_ik, e_ij}
}

// Geometry pass in sorted order: fully coalesced 80B gT rows.
__global__ __launch_bounds__(256) void geom_kernel(const int2* __restrict__ seik2,
                                                   const float* __restrict__ edge_vectors,
                                                   const float* __restrict__ A1,
                                                   const float* __restrict__ ab1,
                                                   float* __restrict__ gT, int T_) {
  int t = blockIdx.x * blockDim.x + threadIdx.x;
  if (t >= T_) return;
  int2 s = seik2[t];
  const float* vj = edge_vectors + 3 * (size_t)s.y;
  const float* vk = edge_vectors + 3 * (size_t)s.x;
  float jx = vj[0], jy = vj[1], jz = vj[2];
  float kx = vk[0], ky = vk[1], kz = vk[2];
  float lij = fmaxf(__builtin_amdgcn_sqrtf(jx * jx + jy * jy + jz * jz), 1e-6f);
  float lik = fmaxf(__builtin_amdgcn_sqrtf(kx * kx + ky * ky + kz * kz), 1e-6f);
  float cosv = (jx * kx + jy * ky + jz * kz) * __builtin_amdgcn_rcpf(lij * lik);
  cosv = fminf(fmaxf(cosv, -1.f), 1.f);
  union { float4 v4[5]; float f[NB_]; } gr;
#pragma unroll
  for (int k = 0; k < NB_; ++k)
    gr.f[k] = silu_f(lij * A1[k] + lik * A1[NB_ + k] + cosv * A1[2 * NB_ + k] + ab1[k]);
  float4* gp = (float4*)(gT + (size_t)t * NB_);
#pragma unroll
  for (int i = 0; i < 5; ++i) gp[i] = gr.v4[i];
}

// ---------------------------------------------------------------------------
// Flat-streamed segmented reduction. Q gather ring depth 8 (issue ~8 triplets
// = ~480cy ahead of use), eik scalar lookahead at t+8..t+11 (seik2 padded to
// T+16, pad=0). G 2-deep (sequential, L2-friendly). Output rows bf16 packed
// into the FRONT 256B of each 512B d_out row slot.
struct G5 { f32x4 a, b, c, d, e; };

__device__ __forceinline__ G5 loadG(const char* __restrict__ gc, int t) {
  const f32x4* p = (const f32x4*)(
      gc + 80u * (unsigned)__builtin_amdgcn_readfirstlane(t));
  G5 g;
  g.a = p[0]; g.b = p[1]; g.c = p[2]; g.d = p[3]; g.e = p[4];
  return g;
}

__device__ __forceinline__ void body_acc(f32x2& acc, const f32x2 base,
                                         const G5& G, unsigned qw,
                                         const f32x2* __restrict__ m) {
  const float* Gf = (const float*)&G;
  f32x2 u = base + bfpair(qw);
  f32x2 ub = fsplat(0.f);
#pragma unroll
  for (int k = 0; k < NB_; k += 2) {
    u  += fsplat(Gf[k])     * m[k];
    ub += fsplat(Gf[k + 1]) * m[k + 1];
  }
  u += ub;
  acc += silu2(u);
}

__global__ __launch_bounds__(256, 6) void seg_kernel(
    const int* __restrict__ offs, const int2* __restrict__ seik2,
    const float* __restrict__ gT,
    const float* __restrict__ Mfold, const float* __restrict__ b1p,
    const unsigned short* __restrict__ P, const unsigned short* __restrict__ Q,
    const int* __restrict__ wstart,
    char* __restrict__ s_out, int E, int NW) {
  const int lane = threadIdx.x & 63;
  const int w = __builtin_amdgcn_readfirstlane(
      (int)((blockIdx.x * blockDim.x + threadIdx.x) >> 6));
  if (w >= NW) return;

  f32x2 m[NB_];
#pragma unroll
  for (int k = 0; k < NB_; ++k) {
    float2 t2 = *(const float2*)(Mfold + k * D_ + 2 * lane);
    m[k] = (f32x2){t2.x, t2.y};
  }
  const float2 bbt = *(const float2*)(b1p + 2 * lane);
  const f32x2 bb = (f32x2){bbt.x, bbt.y};

  int es = (w == 0) ? 0 : wstart[w];
  int ee = (w == NW - 1) ? E : wstart[w + 1];
  if (es >= ee) return;

  const char* Qc = (const char*)Q;
  const char* Pc = (const char*)P;
  const char* gc = (const char*)gT;
  const unsigned loff = (unsigned)lane * 4u;

  int e = es;
  int t = offs[es];
  const int tend = offs[ee];
  int nxt = offs[es + 1];

  unsigned pp = *(const unsigned*)(Pc + ((unsigned)e << 8) + loff);
  int epn = (e + 1 < E) ? e + 1 : E - 1;
  unsigned ppn = *(const unsigned*)(Pc + ((unsigned)epn << 8) + loff);
  f32x2 base = bfpair(pp) + bb;
  f32x2 acc = (f32x2){0.f, 0.f};

  if (t < tend) {
    // init: issue Q gathers for t..t+7, eik lookahead for t+8..t+11
    int i0 = seik2[__builtin_amdgcn_readfirstlane(t)].x;
    int i1 = seik2[__builtin_amdgcn_readfirstlane(t + 1)].x;
    int i2 = seik2[__builtin_amdgcn_readfirstlane(t + 2)].x;
    int i3 = seik2[__builtin_amdgcn_readfirstlane(t + 3)].x;
    int i4 = seik2[__builtin_amdgcn_readfirstlane(t + 4)].x;
    int i5 = seik2[__builtin_amdgcn_readfirstlane(t + 5)].x;
    int i6 = seik2[__builtin_amdgcn_readfirstlane(t + 6)].x;
    int i7 = seik2[__builtin_amdgcn_readfirstlane(t + 7)].x;
    unsigned q0 = *(const unsigned*)(Qc + ((unsigned)i0 << 8) + loff);
    unsigned q1 = *(const unsigned*)(Qc + ((unsigned)i1 << 8) + loff);
    unsigned q2 = *(const unsigned*)(Qc + ((unsigned)i2 << 8) + loff);
    unsigned q3 = *(const unsigned*)(Qc + ((unsigned)i3 << 8) + loff);
    unsigned q4 = *(const unsigned*)(Qc + ((unsigned)i4 << 8) + loff);
    unsigned q5 = *(const unsigned*)(Qc + ((unsigned)i5 << 8) + loff);
    unsigned q6 = *(const unsigned*)(Qc + ((unsigned)i6 << 8) + loff);
    unsigned q7 = *(const unsigned*)(Qc + ((unsigned)i7 << 8) + loff);
    int ekA = seik2[__builtin_amdgcn_readfirstlane(t + 8)].x;
    int ekB = seik2[__builtin_amdgcn_readfirstlane(t + 9)].x;
    int ekC = seik2[__builtin_amdgcn_readfirstlane(t + 10)].x;
    int ekD = seik2[__builtin_amdgcn_readfirstlane(t + 11)].x;
    G5 Ga = loadG(gc, t);
    G5 Gb = loadG(gc, t + 1);

    while (t < tend) {
      // ---- even triplet (consumes Ga, q0) ----
      while (t == nxt) {
        *(unsigned*)(s_out + ((size_t)e << 9) + loff) = packbf(acc);
        acc = (f32x2){0.f, 0.f};
        ++e;
        nxt = offs[e + 1];
        base = bfpair(ppn) + bb;
        int ep = (e + 1 < E) ? e + 1 : E - 1;
        ppn = *(const unsigned*)(Pc + ((unsigned)ep << 8) + loff);
      }
      body_acc(acc, base, Ga, q0, m);
      q0 = q1; q1 = q2; q2 = q3; q3 = q4; q4 = q5; q5 = q6; q6 = q7;
      q7 = *(const unsigned*)(Qc + ((unsigned)ekA << 8) + loff);
      ekA = ekB; ekB = ekC; ekC = ekD;
      ekD = seik2[__builtin_amdgcn_readfirstlane(t + 12)].x;
      Ga = loadG(gc, t + 2);
      ++t;
      if (t >= tend) break;
      // ---- odd triplet (consumes Gb, q0) ----
      while (t == nxt) {
        *(unsigned*)(s_out + ((size_t)e << 9) + loff) = packbf(acc);
        acc = (f32x2){0.f, 0.f};
        ++e;
        nxt = offs[e + 1];
        base = bfpair(ppn) + bb;
        int ep = (e + 1 < E) ? e + 1 : E - 1;
        ppn = *(const unsigned*)(Pc + ((unsigned)ep << 8) + loff);
      }
      body_acc(acc, base, Gb, q0, m);
      q0 = q1; q1 = q2; q2 = q3; q3 = q4; q4 = q5; q5 = q6; q6 = q7;
      q7 = *(const unsigned*)(Qc + ((unsigned)ekA << 8) + loff);
      ekA = ekB; ekB = ekC; ekC = ekD;
      ekD = seik2[__builtin_amdgcn_readfirstlane(t + 12)].x;
      Gb = loadG(gc, t + 2);
      ++t;
    }
  }
  // flush current segment and any trailing empty segments in [e, ee)
  while (e < ee) {
    *(unsigned*)(s_out + ((size_t)e << 9) + loff) = packbf(acc);
    acc = (f32x2){0.f, 0.f};
    ++e;
  }
}

// ---------------------------------------------------------------------------
// In-place MFMA: out[e] = s_bf16[e] @ W2u + cnt[e]*c2 + bu.
// s is bf16 in the front 256B of each 512B row slot of io; each wave reads
// its own 16 rows fully before writing them.
__global__ __launch_bounds__(256) void out_mfma(float* __restrict__ io,
                                                const unsigned short* __restrict__ W2uT,
                                                const float* __restrict__ c2,
                                                const float* __restrict__ bu,
                                                const int* __restrict__ cnt, int E) {
  const int lane = threadIdx.x & 63;
  const int wave = threadIdx.x >> 6;
  const int e0 = (blockIdx.x * 4 + wave) * 16;
  if (e0 >= E) return;
  const int row = lane & 15;
  const int quad = lane >> 4;
  int e = e0 + row; if (e >= E) e = E - 1;

  bf16x8 afr[4];
  const char* arow = (const char*)io + ((size_t)e << 9) + quad * 16;
#pragma unroll
  for (int kt = 0; kt < 4; ++kt)
    afr[kt] = *(const bf16x8*)(arow + kt * 64);

  float nf[4];
#pragma unroll
  for (int i = 0; i < 4; ++i) {
    int er = e0 + quad * 4 + i;
    nf[i] = (float)cnt[(er < E) ? er : (E - 1)];
  }
#pragma unroll
  for (int nt = 0; nt < 8; ++nt) {
    const unsigned short* wrow = W2uT + ((size_t)(nt * 16 + row)) * 128 + quad * 8;
    f32x4 acc = {0.f, 0.f, 0.f, 0.f};
#pragma unroll
    for (int kt = 0; kt < 4; ++kt) {
      bf16x8 bfr = *(const bf16x8*)(wrow + kt * 32);
      acc = __builtin_amdgcn_mfma_f32_16x16x32_bf16(afr[kt], bfr, acc, 0, 0, 0);
    }
    int n = nt * 16 + row;
    float c2n = c2[n], bun = bu[n];
#pragma unroll
    for (int i = 0; i < 4; ++i) {
      int er = e0 + quad * 4 + i;
      if (er < E) io[(size_t)er * D_ + n] = acc[i] + nf[i] * c2n + bun;
    }
  }
}

// ---------------------------------------------------------------------------
extern "C" void kernel_launch(void* const* d_in, const int* in_sizes, int n_in,
                              void* d_out, int out_size, void* d_ws, size_t ws_size,
                              hipStream_t stream) {
  const float* edge_attr    = (const float*)d_in[0];
  const int*   tbe          = (const int*)d_in[2];
  const float* edge_vectors = (const float*)d_in[3];
  const float* A1  = (const float*)d_in[4];
  const float* ab1 = (const float*)d_in[5];
  const float* A2  = (const float*)d_in[6];
  const float* ab2 = (const float*)d_in[7];
  const float* W1  = (const float*)d_in[8];
  const float* b1  = (const float*)d_in[9];
  const float* W2  = (const float*)d_in[10];
  const float* b2  = (const float*)d_in[11];
  const float* Wu  = (const float*)d_in[12];
  const float* bu  = (const float*)d_in[13];
  const int E = in_sizes[0] / D_;
  const int T = in_sizes[2] / 2;
  float* out = (float*)d_out;

  char* w = (char*)d_ws;
  auto carve = [&](size_t bytes) -> char* {
    char* p = w;
    w += (bytes + 255) & ~(size_t)255;
    return p;
  };
  unsigned short* P = (unsigned short*)carve((size_t)E * D_ * 2);
  unsigned short* Q = (unsigned short*)carve((size_t)E * D_ * 2);
  float* gT   = (float*)carve(((size_t)T + 16) * NB_ * 4);  // +16 pad rows (unread values)
  int2* seik2 = (int2*)carve(((size_t)T + 16) * 8);         // +16 pad pairs (zeroed in scan3_wfill)
  int* cnt    = (int*)carve((size_t)E * 4);
  int* pre    = (int*)carve((size_t)E * 4);
  int* offs   = (int*)carve((size_t)(E + 1) * 4);
  int* cursor = (int*)carve((size_t)E * 4);
  int* bsum   = (int*)carve(1024 * 4);
  int* wstart = (int*)carve((size_t)NWAVES * 4);
  float* Mfold = (float*)carve(NB_ * D_ * 4);
  float* b1p   = (float*)carve(D_ * 4);
  unsigned short* W2uT = (unsigned short*)carve(D_ * D_ * 2);
  float* c2    = (float*)carve(D_ * 4);
  unsigned short* W1T = (unsigned short*)carve(256 * 128 * 2);

  const int nb_scan = (E + SCAN_B - 1) / SCAN_B;

  hipMemsetAsync(cnt, 0, (size_t)E * 4, stream);

  prep_kernel<<<(51968 + 255) / 256, 256, 0, stream>>>(A2, ab2, W1, b1, W2, Wu, b2,
                                                       Mfold, b1p, W2uT, c2, W1T);
  pq_mfma<<<(E + 63) / 64, 256, 0, stream>>>(edge_attr, W1T, P, Q, E);

  hist_kernel<<<(T + 255) / 256, 256, 0, stream>>>(tbe, cnt, T);
  scan1_kernel<<<nb_scan, SCAN_B, 0, stream>>>(cnt, pre, bsum, E);
  scan2_kernel<<<1, 256, 0, stream>>>(bsum, nb_scan);
  scan3_wfill<<<nb_scan, SCAN_B, 0, stream>>>(pre, bsum, offs, cursor, seik2,
                                              wstart, E, T, NWAVES);
  scatter_kernel<<<(T + 255) / 256, 256, 0, stream>>>(tbe, cursor, seik2, T);
  geom_kernel<<<(T + 255) / 256, 256, 0, stream>>>(seik2, edge_vectors, A1, ab1, gT, T);

  seg_kernel<<<SEG_BLOCKS, 256, 0, stream>>>(offs, seik2, gT, Mfold, b1p, P, Q,
                                             wstart, (char*)out, E, NWAVES);
  out_mfma<<<(E + 63) / 64, 256, 0, stream>>>(out, W2uT, c2, bu, cnt, E);
}

// Round 6
// 624.173 us; speedup vs baseline: 1.2961x; 1.0772x over previous
//
#include <hip/hip_runtime.h>
#include <stdint.h>

#define D_ 128
#define NB_ 20
#define SCAN_B 1024
#define SEG_BLOCKS 2048
#define NWAVES (SEG_BLOCKS * 256 / 64)

typedef __bf16 bf16x8 __attribute__((ext_vector_type(8)));
typedef float f32x4 __attribute__((ext_vector_type(4)));
typedef float f32x2 __attribute__((ext_vector_type(2)));

// fast silu: x * rcp(1+exp(-x)); v_rcp_f32 rel-err ~2^-22, fine at bf16 tolerance
__device__ __forceinline__ float silu_f(float x) {
  return x * __builtin_amdgcn_rcpf(1.0f + __expf(-x));
}
__device__ __forceinline__ f32x2 silu2(f32x2 x) {
  return (f32x2){silu_f(x.x), silu_f(x.y)};
}
__device__ __forceinline__ f32x2 fsplat(float x) { return (f32x2){x, x}; }

__device__ __forceinline__ unsigned short f2bf(float f) {
  unsigned int x = __float_as_uint(f);
  return (unsigned short)((x + 0x7fffu + ((x >> 16) & 1u)) >> 16);
}
// unpack a uint holding two bf16 (low, high) into f32x2
__device__ __forceinline__ f32x2 bfpair(unsigned u) {
  return (f32x2){__uint_as_float(u << 16), __uint_as_float(u & 0xffff0000u)};
}
__device__ __forceinline__ unsigned packbf(f32x2 v) {
  return ((unsigned)f2bf(v.y) << 16) | (unsigned)f2bf(v.x);
}

// ---------------------------------------------------------------------------
// prep ranges:
//  [0, 2688):           Mfold = A2@W1c (20x128), b1p = b1 + ab2@W1c
//  [2688, 19072):       W2uT bf16: W2uT[n*128+k] = (W2@Wu)[k][n]
//  [19072, 19200):      c2 = b2 @ Wu
//  [19200, 51968):      W1T bf16: W1T[half*128+n][k] = W1[half*128+k][n]
__global__ __launch_bounds__(256) void prep_kernel(
    const float* __restrict__ A2, const float* __restrict__ ab2,
    const float* __restrict__ W1, const float* __restrict__ b1,
    const float* __restrict__ W2, const float* __restrict__ Wu,
    const float* __restrict__ b2,
    float* __restrict__ Mfold, float* __restrict__ b1p,
    unsigned short* __restrict__ W2uT, float* __restrict__ c2,
    unsigned short* __restrict__ W1T) {
  int tid = blockIdx.x * blockDim.x + threadIdx.x;
  if (tid < 21 * D_) {
    int r = tid >> 7, c = tid & (D_ - 1);
    if (r < NB_) {
      float acc = 0.f;
      for (int j = 0; j < NB_; ++j) acc += A2[r * NB_ + j] * W1[(2 * D_ + j) * D_ + c];
      Mfold[r * D_ + c] = acc;
    } else {
      float acc = b1[c];
      for (int j = 0; j < NB_; ++j) acc += ab2[j] * W1[(2 * D_ + j) * D_ + c];
      b1p[c] = acc;
    }
  } else if (tid < 2688 + 16384) {
    int i = tid - 2688;
    // k uniform per 128-thread group (broadcast reads of W2 row), n coalesced
    int n = i & 127, k = i >> 7;
    float acc = 0.f;
    for (int m = 0; m < D_; ++m) acc += W2[k * D_ + m] * Wu[m * D_ + n];
    W2uT[n * 128 + k] = f2bf(acc);
  } else if (tid < 19072 + 128) {
    int n = tid - 19072;
    float acc = 0.f;
    for (int m = 0; m < D_; ++m) acc += b2[m] * Wu[m * D_ + n];
    c2[n] = acc;
  } else if (tid < 19200 + 32768) {
    int i = tid - 19200;
    int r = i >> 7, k = i & 127;
    int half = r >> 7, n = r & 127;
    W1T[i] = f2bf(W1[(size_t)(half * 128 + k) * D_ + n]);
  }
}

// ---------------------------------------------------------------------------
// MFMA pq: P = edge_attr @ W1[0:128], Q = edge_attr @ W1[128:256], bf16 out.
__global__ __launch_bounds__(256) void pq_mfma(const float* __restrict__ edge_attr,
                                               const unsigned short* __restrict__ W1T,
                                               unsigned short* __restrict__ P,
                                               unsigned short* __restrict__ Q, int E) {
  const int lane = threadIdx.x & 63;
  const int wave = threadIdx.x >> 6;
  const int e0 = (blockIdx.x * 4 + wave) * 16;
  if (e0 >= E) return;
  const int row = lane & 15;
  const int quad = lane >> 4;
  int e = e0 + row; if (e >= E) e = E - 1;

  union { bf16x8 v; unsigned short u[8]; } afr[4];
  const float* arow = edge_attr + (size_t)e * D_ + quad * 8;
#pragma unroll
  for (int kt = 0; kt < 4; ++kt) {
    float4 f0 = *(const float4*)(arow + kt * 32);
    float4 f1 = *(const float4*)(arow + kt * 32 + 4);
    afr[kt].u[0] = f2bf(f0.x); afr[kt].u[1] = f2bf(f0.y);
    afr[kt].u[2] = f2bf(f0.z); afr[kt].u[3] = f2bf(f0.w);
    afr[kt].u[4] = f2bf(f1.x); afr[kt].u[5] = f2bf(f1.y);
    afr[kt].u[6] = f2bf(f1.z); afr[kt].u[7] = f2bf(f1.w);
  }
#pragma unroll
  for (int half = 0; half < 2; ++half) {
    unsigned short* Obase = half ? Q : P;
#pragma unroll
    for (int nt = 0; nt < 8; ++nt) {
      const unsigned short* wrow =
          W1T + ((size_t)(half * 128 + nt * 16 + row)) * 128 + quad * 8;
      f32x4 acc = {0.f, 0.f, 0.f, 0.f};
#pragma unroll
      for (int kt = 0; kt < 4; ++kt) {
        bf16x8 bfr = *(const bf16x8*)(wrow + kt * 32);
        acc = __builtin_amdgcn_mfma_f32_16x16x32_bf16(afr[kt].v, bfr, acc, 0, 0, 0);
      }
      int n = nt * 16 + row;
#pragma unroll
      for (int i = 0; i < 4; ++i) {
        int er = e0 + quad * 4 + i;
        if (er < E) Obase[(size_t)er * D_ + n] = f2bf(acc[i]);
      }
    }
  }
}

// ---------------------------------------------------------------------------
// Counting sort by e_ij
__global__ void hist_kernel(const int* __restrict__ tbe, int* __restrict__ cnt, int T_) {
  int t = blockIdx.x * blockDim.x + threadIdx.x;
  if (t < T_) atomicAdd(&cnt[((const int2*)tbe)[t].x], 1);
}

__global__ __launch_bounds__(SCAN_B) void scan1_kernel(const int* __restrict__ cnt,
                                                       int* __restrict__ pre,
                                                       int* __restrict__ bsum, int E) {
  __shared__ int lds[SCAN_B];
  int tid = threadIdx.x, i = blockIdx.x * SCAN_B + tid;
  int v = (i < E) ? cnt[i] : 0;
  lds[tid] = v;
  __syncthreads();
  for (int d = 1; d < SCAN_B; d <<= 1) {
    int add = (tid >= d) ? lds[tid - d] : 0;
    __syncthreads();
    lds[tid] += add;
    __syncthreads();
  }
  if (i < E) pre[i] = lds[tid] - v;
  if (tid == SCAN_B - 1) bsum[blockIdx.x] = lds[tid];
}

__global__ void scan2_kernel(int* __restrict__ bsum, int nb) {
  __shared__ int lds[256];
  int tid = threadIdx.x;
  int v = (tid < nb) ? bsum[tid] : 0;
  lds[tid] = v;
  __syncthreads();
  for (int d = 1; d < 256; d <<= 1) {
    int add = (tid >= d) ? lds[tid - d] : 0;
    __syncthreads();
    lds[tid] += add;
    __syncthreads();
  }
  if (tid < nb) bsum[tid] = lds[tid] - v;
}

// scan3 + wfill + seik2-pad-zero fused.
__global__ __launch_bounds__(SCAN_B) void scan3_wfill(
    const int* __restrict__ pre, const int* __restrict__ bsum,
    int* __restrict__ offs, int* __restrict__ cursor,
    int2* __restrict__ seik2, int* __restrict__ wstart,
    int E, int T_, int NW) {
  int i = blockIdx.x * SCAN_B + threadIdx.x;
  if (i < E) {
    int o = pre[i] + bsum[blockIdx.x];
    offs[i] = o;
    cursor[i] = o;
    int onext = (i + 1 < E) ? (pre[i + 1] + bsum[(i + 1) >> 10]) : T_;
    unsigned long long a = (unsigned long long)o * (unsigned long long)NW;
    unsigned long long b = (unsigned long long)onext * (unsigned long long)NW;
    int w_lo = (int)((a + T_ - 1) / (unsigned long long)T_);
    int w_hi = (int)((b + T_ - 1) / (unsigned long long)T_);
    for (int w = w_lo; w < w_hi; ++w) wstart[w] = i;
  }
  if (i == 0) offs[E] = T_;
  if (i < 24) seik2[T_ + i] = make_int2(0, 0);
}

// Light scatter: only the 8B index pair goes to the random position.
__global__ void scatter_kernel(const int* __restrict__ tbe, int* __restrict__ cursor,
                               int2* __restrict__ seik2, int T_) {
  int t = blockIdx.x * blockDim.x + threadIdx.x;
  if (t >= T_) return;
  int2 v = ((const int2*)tbe)[t];
  int pos = atomicAdd(&cursor[v.x], 1);
  seik2[pos] = make_int2(v.y, v.x);  // {e_ik, e_ij}
}

// Geometry pass in sorted order: g packed bf16 (10 uints), 48B row stride.
__global__ __launch_bounds__(256) void geom_kernel(const int2* __restrict__ seik2,
                                                   const float* __restrict__ edge_vectors,
                                                   const float* __restrict__ A1,
                                                   const float* __restrict__ ab1,
                                                   char* __restrict__ gT, int T_) {
  int t = blockIdx.x * blockDim.x + threadIdx.x;
  if (t >= T_) return;
  int2 s = seik2[t];
  const float* vj = edge_vectors + 3 * (size_t)s.y;
  const float* vk = edge_vectors + 3 * (size_t)s.x;
  float jx = vj[0], jy = vj[1], jz = vj[2];
  float kx = vk[0], ky = vk[1], kz = vk[2];
  float lij = fmaxf(__builtin_amdgcn_sqrtf(jx * jx + jy * jy + jz * jz), 1e-6f);
  float lik = fmaxf(__builtin_amdgcn_sqrtf(kx * kx + ky * ky + kz * kz), 1e-6f);
  float cosv = (jx * kx + jy * ky + jz * kz) * __builtin_amdgcn_rcpf(lij * lik);
  cosv = fminf(fmaxf(cosv, -1.f), 1.f);
  float g[NB_];
#pragma unroll
  for (int k = 0; k < NB_; ++k)
    g[k] = silu_f(lij * A1[k] + lik * A1[NB_ + k] + cosv * A1[2 * NB_ + k] + ab1[k]);
  unsigned wv[10];
#pragma unroll
  for (int j = 0; j < 10; ++j)
    wv[j] = packbf((f32x2){g[2 * j], g[2 * j + 1]});
  uint4* gp = (uint4*)(gT + (size_t)t * 48);
  gp[0] = make_uint4(wv[0], wv[1], wv[2], wv[3]);
  gp[1] = make_uint4(wv[4], wv[5], wv[6], wv[7]);
  gp[2] = make_uint4(wv[8], wv[9], wv[8], wv[9]);  // 8B pad within stride
}

// ---------------------------------------------------------------------------
// Flat-streamed segmented reduction, SHIFT-FREE 8-deep Q pipeline:
// triplets processed in unroll-8 blocks; q[8]/ek[4] statically indexed so a
// gather issued at slot i is consumed 8 triplets later with no register
// rotation (no vmcnt wait on younger loads). G packed bf16, 2-deep.
__device__ __forceinline__ void loadGb(const char* __restrict__ gc, int t,
                                       unsigned* __restrict__ g) {
  const uint4* p = (const uint4*)(
      gc + 48u * (unsigned)__builtin_amdgcn_readfirstlane(t));
  uint4 a = p[0], b = p[1];
  uint2 c = *(const uint2*)(p + 2);
  g[0] = a.x; g[1] = a.y; g[2] = a.z; g[3] = a.w;
  g[4] = b.x; g[5] = b.y; g[6] = b.z; g[7] = b.w;
  g[8] = c.x; g[9] = c.y;
}

__device__ __forceinline__ void body_acc(f32x2& acc, const f32x2 base,
                                         const unsigned* __restrict__ gw,
                                         unsigned qw,
                                         const f32x2* __restrict__ m) {
  f32x2 u = base + bfpair(qw);
  f32x2 ub = fsplat(0.f);
#pragma unroll
  for (int j = 0; j < 10; ++j) {
    unsigned wj = gw[j];
    u  += fsplat(__uint_as_float(wj << 16))         * m[2 * j];
    ub += fsplat(__uint_as_float(wj & 0xffff0000u)) * m[2 * j + 1];
  }
  u += ub;
  acc += silu2(u);
}

__global__ __launch_bounds__(256, 4) void seg_kernel(
    const int* __restrict__ offs, const int2* __restrict__ seik2,
    const char* __restrict__ gT,
    const float* __restrict__ Mfold, const float* __restrict__ b1p,
    const unsigned short* __restrict__ P, const unsigned short* __restrict__ Q,
    const int* __restrict__ wstart,
    char* __restrict__ s_out, int E, int NW) {
  const int lane = threadIdx.x & 63;
  const int w = __builtin_amdgcn_readfirstlane(
      (int)((blockIdx.x * blockDim.x + threadIdx.x) >> 6));
  if (w >= NW) return;

  f32x2 m[NB_];
#pragma unroll
  for (int k = 0; k < NB_; ++k) {
    float2 t2 = *(const float2*)(Mfold + k * D_ + 2 * lane);
    m[k] = (f32x2){t2.x, t2.y};
  }
  const float2 bbt = *(const float2*)(b1p + 2 * lane);
  const f32x2 bb = (f32x2){bbt.x, bbt.y};

  int es = (w == 0) ? 0 : wstart[w];
  int ee = (w == NW - 1) ? E : wstart[w + 1];
  if (es >= ee) return;

  const char* Qc = (const char*)Q;
  const char* Pc = (const char*)P;
  const unsigned loff = (unsigned)lane * 4u;

  int e = es;
  int t = offs[es];
  const int tend = offs[ee];
  int nxt = offs[es + 1];

  unsigned pp0 = *(const unsigned*)(Pc + ((unsigned)e << 8) + loff);
  f32x2 base = bfpair(pp0) + bb;
  int ep = (e + 1 < E) ? e + 1 : E - 1;
  unsigned ppn = *(const unsigned*)(Pc + ((unsigned)ep << 8) + loff);
  f32x2 acc = (f32x2){0.f, 0.f};

#define SEG_FLUSH()                                                        \
  do {                                                                     \
    *(unsigned*)(s_out + ((size_t)e << 9) + loff) = packbf(acc);           \
    acc = (f32x2){0.f, 0.f};                                               \
    ++e;                                                                   \
    nxt = offs[e + 1];                                                     \
    base = bfpair(ppn) + bb;                                               \
    int ep2 = (e + 1 < E) ? e + 1 : E - 1;                                 \
    ppn = *(const unsigned*)(Pc + ((unsigned)ep2 << 8) + loff);            \
  } while (0)

  if (t < tend) {
    unsigned q[8];
    int ek[4];
    unsigned G0[10], G1[10];
    // prologue: q[i] = Q row for triplet t+i; ek[j] = eik(t+8+j)
#pragma unroll
    for (int i = 0; i < 8; ++i) {
      int ei = seik2[__builtin_amdgcn_readfirstlane(t + i)].x;
      q[i] = *(const unsigned*)(Qc + ((unsigned)ei << 8) + loff);
    }
#pragma unroll
    for (int j = 0; j < 4; ++j)
      ek[j] = seik2[__builtin_amdgcn_readfirstlane(t + 8 + j)].x;
    loadGb(gT, t, G0);
    loadGb(gT, t + 1, G1);

    while (t + 8 <= tend) {
#pragma unroll
      for (int i = 0; i < 8; ++i) {
        while (t == nxt) SEG_FLUSH();
        body_acc(acc, base, (i & 1) ? G1 : G0, q[i], m);
        if (i & 1) loadGb(gT, t + 2, G1); else loadGb(gT, t + 2, G0);
        int ekv = ek[i & 3];  // eik(t+8)
        q[i] = *(const unsigned*)(Qc + ((unsigned)ekv << 8) + loff);
        ek[i & 3] = seik2[__builtin_amdgcn_readfirstlane(t + 12)].x;
        ++t;
      }
    }
    // epilogue: 0..7 remaining triplets, q[0..rem-1] already loaded
#pragma unroll
    for (int i = 0; i < 8; ++i) {
      if (t < tend) {
        while (t == nxt) SEG_FLUSH();
        unsigned Gt[10];
        loadGb(gT, t, Gt);
        body_acc(acc, base, Gt, q[i], m);
        ++t;
      }
    }
  }
#undef SEG_FLUSH
  // flush current segment and any trailing empty segments in [e, ee)
  while (e < ee) {
    *(unsigned*)(s_out + ((size_t)e << 9) + loff) = packbf(acc);
    acc = (f32x2){0.f, 0.f};
    ++e;
  }
}

// ---------------------------------------------------------------------------
// In-place MFMA: out[e] = s_bf16[e] @ W2u + cnt[e]*c2 + bu.
// s is bf16 in the front 256B of each 512B row slot of io; each wave reads
// its own 16 rows fully before writing them.
__global__ __launch_bounds__(256) void out_mfma(float* __restrict__ io,
                                                const unsigned short* __restrict__ W2uT,
                                                const float* __restrict__ c2,
                                                const float* __restrict__ bu,
                                                const int* __restrict__ cnt, int E) {
  const int lane = threadIdx.x & 63;
  const int wave = threadIdx.x >> 6;
  const int e0 = (blockIdx.x * 4 + wave) * 16;
  if (e0 >= E) return;
  const int row = lane & 15;
  const int quad = lane >> 4;
  int e = e0 + row; if (e >= E) e = E - 1;

  bf16x8 afr[4];
  const char* arow = (const char*)io + ((size_t)e << 9) + quad * 16;
#pragma unroll
  for (int kt = 0; kt < 4; ++kt)
    afr[kt] = *(const bf16x8*)(arow + kt * 64);

  float nf[4];
#pragma unroll
  for (int i = 0; i < 4; ++i) {
    int er = e0 + quad * 4 + i;
    nf[i] = (float)cnt[(er < E) ? er : (E - 1)];
  }
#pragma unroll
  for (int nt = 0; nt < 8; ++nt) {
    const unsigned short* wrow = W2uT + ((size_t)(nt * 16 + row)) * 128 + quad * 8;
    f32x4 acc = {0.f, 0.f, 0.f, 0.f};
#pragma unroll
    for (int kt = 0; kt < 4; ++kt) {
      bf16x8 bfr = *(const bf16x8*)(wrow + kt * 32);
      acc = __builtin_amdgcn_mfma_f32_16x16x32_bf16(afr[kt], bfr, acc, 0, 0, 0);
    }
    int n = nt * 16 + row;
    float c2n = c2[n], bun = bu[n];
#pragma unroll
    for (int i = 0; i < 4; ++i) {
      int er = e0 + quad * 4 + i;
      if (er < E) io[(size_t)er * D_ + n] = acc[i] + nf[i] * c2n + bun;
    }
  }
}

// ---------------------------------------------------------------------------
extern "C" void kernel_launch(void* const* d_in, const int* in_sizes, int n_in,
                              void* d_out, int out_size, void* d_ws, size_t ws_size,
                              hipStream_t stream) {
  const float* edge_attr    = (const float*)d_in[0];
  const int*   tbe          = (const int*)d_in[2];
  const float* edge_vectors = (const float*)d_in[3];
  const float* A1  = (const float*)d_in[4];
  const float* ab1 = (const float*)d_in[5];
  const float* A2  = (const float*)d_in[6];
  const float* ab2 = (const float*)d_in[7];
  const float* W1  = (const float*)d_in[8];
  const float* b1  = (const float*)d_in[9];
  const float* W2  = (const float*)d_in[10];
  const float* b2  = (const float*)d_in[11];
  const float* Wu  = (const float*)d_in[12];
  const float* bu  = (const float*)d_in[13];
  const int E = in_sizes[0] / D_;
  const int T = in_sizes[2] / 2;
  float* out = (float*)d_out;

  char* w = (char*)d_ws;
  auto carve = [&](size_t bytes) -> char* {
    char* p = w;
    w += (bytes + 255) & ~(size_t)255;
    return p;
  };
  unsigned short* P = (unsigned short*)carve((size_t)E * D_ * 2);
  unsigned short* Q = (unsigned short*)carve((size_t)E * D_ * 2);
  char* gT    = carve(((size_t)T + 24) * 48);               // packed bf16 g, 48B rows
  int2* seik2 = (int2*)carve(((size_t)T + 24) * 8);         // +24 pad pairs (zeroed in scan3_wfill)
  int* cnt    = (int*)carve((size_t)E * 4);
  int* pre    = (int*)carve((size_t)E * 4);
  int* offs   = (int*)carve((size_t)(E + 1) * 4);
  int* cursor = (int*)carve((size_t)E * 4);
  int* bsum   = (int*)carve(1024 * 4);
  int* wstart = (int*)carve((size_t)NWAVES * 4);
  float* Mfold = (float*)carve(NB_ * D_ * 4);
  float* b1p   = (float*)carve(D_ * 4);
  unsigned short* W2uT = (unsigned short*)carve(D_ * D_ * 2);
  float* c2    = (float*)carve(D_ * 4);
  unsigned short* W1T = (unsigned short*)carve(256 * 128 * 2);

  const int nb_scan = (E + SCAN_B - 1) / SCAN_B;

  hipMemsetAsync(cnt, 0, (size_t)E * 4, stream);

  prep_kernel<<<(51968 + 255) / 256, 256, 0, stream>>>(A2, ab2, W1, b1, W2, Wu, b2,
                                                       Mfold, b1p, W2uT, c2, W1T);
  pq_mfma<<<(E + 63) / 64, 256, 0, stream>>>(edge_attr, W1T, P, Q, E);

  hist_kernel<<<(T + 255) / 256, 256, 0, stream>>>(tbe, cnt, T);
  scan1_kernel<<<nb_scan, SCAN_B, 0, stream>>>(cnt, pre, bsum, E);
  scan2_kernel<<<1, 256, 0, stream>>>(bsum, nb_scan);
  scan3_wfill<<<nb_scan, SCAN_B, 0, stream>>>(pre, bsum, offs, cursor, seik2,
                                              wstart, E, T, NWAVES);
  scatter_kernel<<<(T + 255) / 256, 256, 0, stream>>>(tbe, cursor, seik2, T);
  geom_kernel<<<(T + 255) / 256, 256, 0, stream>>>(seik2, edge_vectors, A1, ab1, gT, T);

  seg_kernel<<<SEG_BLOCKS, 256, 0, stream>>>(offs, seik2, gT, Mfold, b1p, P, Q,
                                             wstart, (char*)out, E, NWAVES);
  out_mfma<<<(E + 63) / 64, 256, 0, stream>>>(out, W2uT, c2, bu, cnt, E);
}

// Round 7
// 599.126 us; speedup vs baseline: 1.3503x; 1.0418x over previous
//
#include <hip/hip_runtime.h>
#include <stdint.h>

#define D_ 128
#define NB_ 20
#define SCAN_B 1024
#define SEG_BLOCKS 2048
#define NWAVES (SEG_BLOCKS * 256 / 64)

typedef __bf16 bf16x8 __attribute__((ext_vector_type(8)));
typedef float f32x4 __attribute__((ext_vector_type(4)));
typedef float f32x2 __attribute__((ext_vector_type(2)));

// fast silu: x * rcp(1+exp(-x)); v_rcp_f32 rel-err ~2^-22, fine at bf16 tolerance
__device__ __forceinline__ float silu_f(float x) {
  return x * __builtin_amdgcn_rcpf(1.0f + __expf(-x));
}
__device__ __forceinline__ f32x2 silu2(f32x2 x) {
  return (f32x2){silu_f(x.x), silu_f(x.y)};
}
__device__ __forceinline__ f32x2 fsplat(float x) { return (f32x2){x, x}; }

__device__ __forceinline__ unsigned short f2bf(float f) {
  unsigned int x = __float_as_uint(f);
  return (unsigned short)((x + 0x7fffu + ((x >> 16) & 1u)) >> 16);
}
// unpack a uint holding two bf16 (low, high) into f32x2
__device__ __forceinline__ f32x2 bfpair(unsigned u) {
  return (f32x2){__uint_as_float(u << 16), __uint_as_float(u & 0xffff0000u)};
}
__device__ __forceinline__ unsigned packbf(f32x2 v) {
  return ((unsigned)f2bf(v.y) << 16) | (unsigned)f2bf(v.x);
}

// ---------------------------------------------------------------------------
// prep ranges:
//  [0, 2688):           Mfold = A2@W1c (20x128), b1p = b1 + ab2@W1c
//  [2688, 19072):       W2uT bf16: W2uT[n*128+k] = (W2@Wu)[k][n]
//  [19072, 19200):      c2 = b2 @ Wu
//  [19200, 51968):      W1T bf16: W1T[half*128+n][k] = W1[half*128+k][n]
__global__ __launch_bounds__(256) void prep_kernel(
    const float* __restrict__ A2, const float* __restrict__ ab2,
    const float* __restrict__ W1, const float* __restrict__ b1,
    const float* __restrict__ W2, const float* __restrict__ Wu,
    const float* __restrict__ b2,
    float* __restrict__ Mfold, float* __restrict__ b1p,
    unsigned short* __restrict__ W2uT, float* __restrict__ c2,
    unsigned short* __restrict__ W1T) {
  int tid = blockIdx.x * blockDim.x + threadIdx.x;
  if (tid < 21 * D_) {
    int r = tid >> 7, c = tid & (D_ - 1);
    if (r < NB_) {
      float acc = 0.f;
      for (int j = 0; j < NB_; ++j) acc += A2[r * NB_ + j] * W1[(2 * D_ + j) * D_ + c];
      Mfold[r * D_ + c] = acc;
    } else {
      float acc = b1[c];
      for (int j = 0; j < NB_; ++j) acc += ab2[j] * W1[(2 * D_ + j) * D_ + c];
      b1p[c] = acc;
    }
  } else if (tid < 2688 + 16384) {
    int i = tid - 2688;
    // k uniform per 128-thread group (broadcast reads of W2 row), n coalesced
    int n = i & 127, k = i >> 7;
    float acc = 0.f;
    for (int m = 0; m < D_; ++m) acc += W2[k * D_ + m] * Wu[m * D_ + n];
    W2uT[n * 128 + k] = f2bf(acc);
  } else if (tid < 19072 + 128) {
    int n = tid - 19072;
    float acc = 0.f;
    for (int m = 0; m < D_; ++m) acc += b2[m] * Wu[m * D_ + n];
    c2[n] = acc;
  } else if (tid < 19200 + 32768) {
    int i = tid - 19200;
    int r = i >> 7, k = i & 127;
    int half = r >> 7, n = r & 127;
    W1T[i] = f2bf(W1[(size_t)(half * 128 + k) * D_ + n]);
  }
}

// ---------------------------------------------------------------------------
// MFMA pq: P = edge_attr @ W1[0:128], Q = edge_attr @ W1[128:256], bf16 out.
// Output staged per-wave in LDS, then stored as full coalesced 256B rows
// (16x fewer write transactions than per-element ushort stores).
#define PQ_PITCH 136  // ushorts; 272B row, 16B-aligned
__global__ __launch_bounds__(256) void pq_mfma(const float* __restrict__ edge_attr,
                                               const unsigned short* __restrict__ W1T,
                                               unsigned short* __restrict__ P,
                                               unsigned short* __restrict__ Q, int E) {
  __shared__ unsigned short tile[4][16 * PQ_PITCH];
  const int lane = threadIdx.x & 63;
  const int wave = threadIdx.x >> 6;
  const int e0 = (blockIdx.x * 4 + wave) * 16;
  if (e0 >= E) return;
  const int row = lane & 15;
  const int quad = lane >> 4;
  int e = e0 + row; if (e >= E) e = E - 1;
  unsigned short* tl = tile[wave];

  union { bf16x8 v; unsigned short u[8]; } afr[4];
  const float* arow = edge_attr + (size_t)e * D_ + quad * 8;
#pragma unroll
  for (int kt = 0; kt < 4; ++kt) {
    float4 f0 = *(const float4*)(arow + kt * 32);
    float4 f1 = *(const float4*)(arow + kt * 32 + 4);
    afr[kt].u[0] = f2bf(f0.x); afr[kt].u[1] = f2bf(f0.y);
    afr[kt].u[2] = f2bf(f0.z); afr[kt].u[3] = f2bf(f0.w);
    afr[kt].u[4] = f2bf(f1.x); afr[kt].u[5] = f2bf(f1.y);
    afr[kt].u[6] = f2bf(f1.z); afr[kt].u[7] = f2bf(f1.w);
  }
#pragma unroll
  for (int half = 0; half < 2; ++half) {
    unsigned short* Obase = half ? Q : P;
#pragma unroll
    for (int nt = 0; nt < 8; ++nt) {
      const unsigned short* wrow =
          W1T + ((size_t)(half * 128 + nt * 16 + row)) * 128 + quad * 8;
      f32x4 acc = {0.f, 0.f, 0.f, 0.f};
#pragma unroll
      for (int kt = 0; kt < 4; ++kt) {
        bf16x8 bfr = *(const bf16x8*)(wrow + kt * 32);
        acc = __builtin_amdgcn_mfma_f32_16x16x32_bf16(afr[kt].v, bfr, acc, 0, 0, 0);
      }
      int n = nt * 16 + row;
#pragma unroll
      for (int i = 0; i < 4; ++i)
        tl[(quad * 4 + i) * PQ_PITCH + n] = f2bf(acc[i]);
    }
    // coalesced store: 4 rows per instruction, 256B contiguous per row
    const int c = lane & 15, q2 = lane >> 4;
#pragma unroll
    for (int blk = 0; blk < 4; ++blk) {
      int r = blk * 4 + q2;
      int er = e0 + r;
      if (er < E) {
        uint4 v = *(const uint4*)(tl + r * PQ_PITCH + c * 8);
        *(uint4*)(Obase + (size_t)er * D_ + c * 8) = v;
      }
    }
  }
}

// ---------------------------------------------------------------------------
// Counting sort by e_ij
__global__ void hist_kernel(const int* __restrict__ tbe, int* __restrict__ cnt, int T_) {
  int t = blockIdx.x * blockDim.x + threadIdx.x;
  if (t < T_) atomicAdd(&cnt[((const int2*)tbe)[t].x], 1);
}

__global__ __launch_bounds__(SCAN_B) void scan1_kernel(const int* __restrict__ cnt,
                                                       int* __restrict__ pre,
                                                       int* __restrict__ bsum, int E) {
  __shared__ int lds[SCAN_B];
  int tid = threadIdx.x, i = blockIdx.x * SCAN_B + tid;
  int v = (i < E) ? cnt[i] : 0;
  lds[tid] = v;
  __syncthreads();
  for (int d = 1; d < SCAN_B; d <<= 1) {
    int add = (tid >= d) ? lds[tid - d] : 0;
    __syncthreads();
    lds[tid] += add;
    __syncthreads();
  }
  if (i < E) pre[i] = lds[tid] - v;
  if (tid == SCAN_B - 1) bsum[blockIdx.x] = lds[tid];
}

__global__ void scan2_kernel(int* __restrict__ bsum, int nb) {
  __shared__ int lds[256];
  int tid = threadIdx.x;
  int v = (tid < nb) ? bsum[tid] : 0;
  lds[tid] = v;
  __syncthreads();
  for (int d = 1; d < 256; d <<= 1) {
    int add = (tid >= d) ? lds[tid - d] : 0;
    __syncthreads();
    lds[tid] += add;
    __syncthreads();
  }
  if (tid < nb) bsum[tid] = lds[tid] - v;
}

// scan3 + wfill + seik2-pad-zero fused.
__global__ __launch_bounds__(SCAN_B) void scan3_wfill(
    const int* __restrict__ pre, const int* __restrict__ bsum,
    int* __restrict__ offs, int* __restrict__ cursor,
    int2* __restrict__ seik2, int* __restrict__ wstart,
    int E, int T_, int NW) {
  int i = blockIdx.x * SCAN_B + threadIdx.x;
  if (i < E) {
    int o = pre[i] + bsum[blockIdx.x];
    offs[i] = o;
    cursor[i] = o;
    int onext = (i + 1 < E) ? (pre[i + 1] + bsum[(i + 1) >> 10]) : T_;
    unsigned long long a = (unsigned long long)o * (unsigned long long)NW;
    unsigned long long b = (unsigned long long)onext * (unsigned long long)NW;
    int w_lo = (int)((a + T_ - 1) / (unsigned long long)T_);
    int w_hi = (int)((b + T_ - 1) / (unsigned long long)T_);
    for (int w = w_lo; w < w_hi; ++w) wstart[w] = i;
  }
  if (i == 0) offs[E] = T_;
  if (i < 24) seik2[T_ + i] = make_int2(0, 0);
}

// Light scatter: only the 8B index pair goes to the random position.
__global__ void scatter_kernel(const int* __restrict__ tbe, int* __restrict__ cursor,
                               int2* __restrict__ seik2, int T_) {
  int t = blockIdx.x * blockDim.x + threadIdx.x;
  if (t >= T_) return;
  int2 v = ((const int2*)tbe)[t];
  int pos = atomicAdd(&cursor[v.x], 1);
  seik2[pos] = make_int2(v.y, v.x);  // {e_ik, e_ij}
}

// Geometry pass in sorted order: g packed bf16 (10 uints), 48B row stride.
__global__ __launch_bounds__(256) void geom_kernel(const int2* __restrict__ seik2,
                                                   const float* __restrict__ edge_vectors,
                                                   const float* __restrict__ A1,
                                                   const float* __restrict__ ab1,
                                                   char* __restrict__ gT, int T_) {
  int t = blockIdx.x * blockDim.x + threadIdx.x;
  if (t >= T_) return;
  int2 s = seik2[t];
  const float* vj = edge_vectors + 3 * (size_t)s.y;
  const float* vk = edge_vectors + 3 * (size_t)s.x;
  float jx = vj[0], jy = vj[1], jz = vj[2];
  float kx = vk[0], ky = vk[1], kz = vk[2];
  float lij = fmaxf(__builtin_amdgcn_sqrtf(jx * jx + jy * jy + jz * jz), 1e-6f);
  float lik = fmaxf(__builtin_amdgcn_sqrtf(kx * kx + ky * ky + kz * kz), 1e-6f);
  float cosv = (jx * kx + jy * ky + jz * kz) * __builtin_amdgcn_rcpf(lij * lik);
  cosv = fminf(fmaxf(cosv, -1.f), 1.f);
  float g[NB_];
#pragma unroll
  for (int k = 0; k < NB_; ++k)
    g[k] = silu_f(lij * A1[k] + lik * A1[NB_ + k] + cosv * A1[2 * NB_ + k] + ab1[k]);
  unsigned wv[10];
#pragma unroll
  for (int j = 0; j < 10; ++j)
    wv[j] = packbf((f32x2){g[2 * j], g[2 * j + 1]});
  uint4* gp = (uint4*)(gT + (size_t)t * 48);
  gp[0] = make_uint4(wv[0], wv[1], wv[2], wv[3]);
  gp[1] = make_uint4(wv[4], wv[5], wv[6], wv[7]);
  gp[2] = make_uint4(wv[8], wv[9], wv[8], wv[9]);  // 8B pad within stride
}

// ---------------------------------------------------------------------------
// Flat-streamed segmented reduction, SHIFT-FREE 8-deep Q pipeline:
// triplets processed in unroll-8 blocks; q[8]/ek[4] statically indexed so a
// gather issued at slot i is consumed 8 triplets later with no register
// rotation (no vmcnt wait on younger loads). G packed bf16, 2-deep.
__device__ __forceinline__ void loadGb(const char* __restrict__ gc, int t,
                                       unsigned* __restrict__ g) {
  const uint4* p = (const uint4*)(
      gc + 48u * (unsigned)__builtin_amdgcn_readfirstlane(t));
  uint4 a = p[0], b = p[1];
  uint2 c = *(const uint2*)(p + 2);
  g[0] = a.x; g[1] = a.y; g[2] = a.z; g[3] = a.w;
  g[4] = b.x; g[5] = b.y; g[6] = b.z; g[7] = b.w;
  g[8] = c.x; g[9] = c.y;
}

__device__ __forceinline__ void body_acc(f32x2& acc, const f32x2 base,
                                         const unsigned* __restrict__ gw,
                                         unsigned qw,
                                         const f32x2* __restrict__ m) {
  f32x2 u = base + bfpair(qw);
  f32x2 ub = fsplat(0.f);
#pragma unroll
  for (int j = 0; j < 10; ++j) {
    unsigned wj = gw[j];
    u  += fsplat(__uint_as_float(wj << 16))         * m[2 * j];
    ub += fsplat(__uint_as_float(wj & 0xffff0000u)) * m[2 * j + 1];
  }
  u += ub;
  acc += silu2(u);
}

__global__ __launch_bounds__(256, 4) void seg_kernel(
    const int* __restrict__ offs, const int2* __restrict__ seik2,
    const char* __restrict__ gT,
    const float* __restrict__ Mfold, const float* __restrict__ b1p,
    const unsigned short* __restrict__ P, const unsigned short* __restrict__ Q,
    const int* __restrict__ wstart,
    char* __restrict__ s_out, int E, int NW) {
  const int lane = threadIdx.x & 63;
  const int w = __builtin_amdgcn_readfirstlane(
      (int)((blockIdx.x * blockDim.x + threadIdx.x) >> 6));
  if (w >= NW) return;

  f32x2 m[NB_];
#pragma unroll
  for (int k = 0; k < NB_; ++k) {
    float2 t2 = *(const float2*)(Mfold + k * D_ + 2 * lane);
    m[k] = (f32x2){t2.x, t2.y};
  }
  const float2 bbt = *(const float2*)(b1p + 2 * lane);
  const f32x2 bb = (f32x2){bbt.x, bbt.y};

  int es = (w == 0) ? 0 : wstart[w];
  int ee = (w == NW - 1) ? E : wstart[w + 1];
  if (es >= ee) return;

  const char* Qc = (const char*)Q;
  const char* Pc = (const char*)P;
  const unsigned loff = (unsigned)lane * 4u;

  int e = es;
  int t = offs[es];
  const int tend = offs[ee];
  int nxt = offs[es + 1];

  unsigned pp0 = *(const unsigned*)(Pc + ((unsigned)e << 8) + loff);
  f32x2 base = bfpair(pp0) + bb;
  int ep = (e + 1 < E) ? e + 1 : E - 1;
  unsigned ppn = *(const unsigned*)(Pc + ((unsigned)ep << 8) + loff);
  f32x2 acc = (f32x2){0.f, 0.f};

#define SEG_FLUSH()                                                        \
  do {                                                                     \
    *(unsigned*)(s_out + ((size_t)e << 9) + loff) = packbf(acc);           \
    acc = (f32x2){0.f, 0.f};                                               \
    ++e;                                                                   \
    nxt = offs[e + 1];                                                     \
    base = bfpair(ppn) + bb;                                               \
    int ep2 = (e + 1 < E) ? e + 1 : E - 1;                                 \
    ppn = *(const unsigned*)(Pc + ((unsigned)ep2 << 8) + loff);            \
  } while (0)

  if (t < tend) {
    unsigned q[8];
    int ek[4];
    unsigned G0[10], G1[10];
    // prologue: q[i] = Q row for triplet t+i; ek[j] = eik(t+8+j)
#pragma unroll
    for (int i = 0; i < 8; ++i) {
      int ei = seik2[__builtin_amdgcn_readfirstlane(t + i)].x;
      q[i] = *(const unsigned*)(Qc + ((unsigned)ei << 8) + loff);
    }
#pragma unroll
    for (int j = 0; j < 4; ++j)
      ek[j] = seik2[__builtin_amdgcn_readfirstlane(t + 8 + j)].x;
    loadGb(gT, t, G0);
    loadGb(gT, t + 1, G1);

    while (t + 8 <= tend) {
#pragma unroll
      for (int i = 0; i < 8; ++i) {
        while (t == nxt) SEG_FLUSH();
        body_acc(acc, base, (i & 1) ? G1 : G0, q[i], m);
        if (i & 1) loadGb(gT, t + 2, G1); else loadGb(gT, t + 2, G0);
        int ekv = ek[i & 3];  // eik(t+8)
        q[i] = *(const unsigned*)(Qc + ((unsigned)ekv << 8) + loff);
        ek[i & 3] = seik2[__builtin_amdgcn_readfirstlane(t + 12)].x;
        ++t;
      }
    }
    // epilogue: 0..7 remaining triplets, q[0..rem-1] already loaded
#pragma unroll
    for (int i = 0; i < 8; ++i) {
      if (t < tend) {
        while (t == nxt) SEG_FLUSH();
        unsigned Gt[10];
        loadGb(gT, t, Gt);
        body_acc(acc, base, Gt, q[i], m);
        ++t;
      }
    }
  }
#undef SEG_FLUSH
  // flush current segment and any trailing empty segments in [e, ee)
  while (e < ee) {
    *(unsigned*)(s_out + ((size_t)e << 9) + loff) = packbf(acc);
    acc = (f32x2){0.f, 0.f};
    ++e;
  }
}

// ---------------------------------------------------------------------------
// In-place MFMA: out[e] = s_bf16[e] @ W2u + cnt[e]*c2 + bu.
// s is bf16 in the front 256B of each 512B row slot of io; each wave reads
// its own 16 rows fully before writing them. Output staged in LDS and
// stored as full coalesced 512B fp32 rows.
#define OUT_PITCH 132  // f32; 528B row, 16B-aligned
__global__ __launch_bounds__(256) void out_mfma(float* __restrict__ io,
                                                const unsigned short* __restrict__ W2uT,
                                                const float* __restrict__ c2,
                                                const float* __restrict__ bu,
                                                const int* __restrict__ cnt, int E) {
  __shared__ float tileF[4][16 * OUT_PITCH];
  const int lane = threadIdx.x & 63;
  const int wave = threadIdx.x >> 6;
  const int e0 = (blockIdx.x * 4 + wave) * 16;
  if (e0 >= E) return;
  const int row = lane & 15;
  const int quad = lane >> 4;
  int e = e0 + row; if (e >= E) e = E - 1;
  float* tl = tileF[wave];

  bf16x8 afr[4];
  const char* arow = (const char*)io + ((size_t)e << 9) + quad * 16;
#pragma unroll
  for (int kt = 0; kt < 4; ++kt)
    afr[kt] = *(const bf16x8*)(arow + kt * 64);

  float nf[4];
#pragma unroll
  for (int i = 0; i < 4; ++i) {
    int er = e0 + quad * 4 + i;
    nf[i] = (float)cnt[(er < E) ? er : (E - 1)];
  }
#pragma unroll
  for (int nt = 0; nt < 8; ++nt) {
    const unsigned short* wrow = W2uT + ((size_t)(nt * 16 + row)) * 128 + quad * 8;
    f32x4 acc = {0.f, 0.f, 0.f, 0.f};
#pragma unroll
    for (int kt = 0; kt < 4; ++kt) {
      bf16x8 bfr = *(const bf16x8*)(wrow + kt * 32);
      acc = __builtin_amdgcn_mfma_f32_16x16x32_bf16(afr[kt], bfr, acc, 0, 0, 0);
    }
    int n = nt * 16 + row;
    float c2n = c2[n], bun = bu[n];
#pragma unroll
    for (int i = 0; i < 4; ++i)
      tl[(quad * 4 + i) * OUT_PITCH + n] = acc[i] + nf[i] * c2n + bun;
  }
  // coalesced store: 2 rows per instruction, 512B contiguous per row
  const int c = lane & 31, h = lane >> 5;
#pragma unroll
  for (int blk = 0; blk < 8; ++blk) {
    int r = blk * 2 + h;
    int er = e0 + r;
    if (er < E) {
      f32x4 v = *(const f32x4*)(tl + r * OUT_PITCH + c * 4);
      *(f32x4*)(io + (size_t)er * D_ + c * 4) = v;
    }
  }
}

// ---------------------------------------------------------------------------
extern "C" void kernel_launch(void* const* d_in, const int* in_sizes, int n_in,
                              void* d_out, int out_size, void* d_ws, size_t ws_size,
                              hipStream_t stream) {
  const float* edge_attr    = (const float*)d_in[0];
  const int*   tbe          = (const int*)d_in[2];
  const float* edge_vectors = (const float*)d_in[3];
  const float* A1  = (const float*)d_in[4];
  const float* ab1 = (const float*)d_in[5];
  const float* A2  = (const float*)d_in[6];
  const float* ab2 = (const float*)d_in[7];
  const float* W1  = (const float*)d_in[8];
  const float* b1  = (const float*)d_in[9];
  const float* W2  = (const float*)d_in[10];
  const float* b2  = (const float*)d_in[11];
  const float* Wu  = (const float*)d_in[12];
  const float* bu  = (const float*)d_in[13];
  const int E = in_sizes[0] / D_;
  const int T = in_sizes[2] / 2;
  float* out = (float*)d_out;

  char* w = (char*)d_ws;
  auto carve = [&](size_t bytes) -> char* {
    char* p = w;
    w += (bytes + 255) & ~(size_t)255;
    return p;
  };
  unsigned short* P = (unsigned short*)carve((size_t)E * D_ * 2);
  unsigned short* Q = (unsigned short*)carve((size_t)E * D_ * 2);
  char* gT    = carve(((size_t)T + 24) * 48);               // packed bf16 g, 48B rows
  int2* seik2 = (int2*)carve(((size_t)T + 24) * 8);         // +24 pad pairs (zeroed in scan3_wfill)
  int* cnt    = (int*)carve((size_t)E * 4);
  int* pre    = (int*)carve((size_t)E * 4);
  int* offs   = (int*)carve((size_t)(E + 1) * 4);
  int* cursor = (int*)carve((size_t)E * 4);
  int* bsum   = (int*)carve(1024 * 4);
  int* wstart = (int*)carve((size_t)NWAVES * 4);
  float* Mfold = (float*)carve(NB_ * D_ * 4);
  float* b1p   = (float*)carve(D_ * 4);
  unsigned short* W2uT = (unsigned short*)carve(D_ * D_ * 2);
  float* c2    = (float*)carve(D_ * 4);
  unsigned short* W1T = (unsigned short*)carve(256 * 128 * 2);

  const int nb_scan = (E + SCAN_B - 1) / SCAN_B;

  hipMemsetAsync(cnt, 0, (size_t)E * 4, stream);

  prep_kernel<<<(51968 + 255) / 256, 256, 0, stream>>>(A2, ab2, W1, b1, W2, Wu, b2,
                                                       Mfold, b1p, W2uT, c2, W1T);
  pq_mfma<<<(E + 63) / 64, 256, 0, stream>>>(edge_attr, W1T, P, Q, E);

  hist_kernel<<<(T + 255) / 256, 256, 0, stream>>>(tbe, cnt, T);
  scan1_kernel<<<nb_scan, SCAN_B, 0, stream>>>(cnt, pre, bsum, E);
  scan2_kernel<<<1, 256, 0, stream>>>(bsum, nb_scan);
  scan3_wfill<<<nb_scan, SCAN_B, 0, stream>>>(pre, bsum, offs, cursor, seik2,
                                              wstart, E, T, NWAVES);
  scatter_kernel<<<(T + 255) / 256, 256, 0, stream>>>(tbe, cursor, seik2, T);
  geom_kernel<<<(T + 255) / 256, 256, 0, stream>>>(seik2, edge_vectors, A1, ab1, gT, T);

  seg_kernel<<<SEG_BLOCKS, 256, 0, stream>>>(offs, seik2, gT, Mfold, b1p, P, Q,
                                             wstart, (char*)out, E, NWAVES);
  out_mfma<<<(E + 63) / 64, 256, 0, stream>>>(out, W2uT, c2, bu, cnt, E);
}